// Round 7
// baseline (563.171 us; speedup 1.0000x reference)
//
#include <hip/hip_runtime.h>
#include <stdint.h>

#define FEAT 128
#define NNODES 512
#define BATCH 4
#define EDGES 97920              // sum_{r=257}^{511} r ; 64 | EDGES
#define BE (BATCH*EDGES)         // 391680
#define NSAMP 5
#define BASE_OFF 32896           // 256*257/2
#define CHUNKS 40                // gumbel blocks per (b,s)
#define NWT (BE/64)              // 6120 wave-tiles (64 edges per wave)
#define MLP_GRID 510             // 510 blocks x 4 waves x 3 tiles = 6120 exactly

// ---------------- threefry2x32 (exact JAX core, key=[0,42]) ------------------
__device__ __forceinline__ void threefry2x32(uint32_t k0, uint32_t k1,
                                             uint32_t& x0, uint32_t& x1) {
  uint32_t k2 = k0 ^ k1 ^ 0x1BD11BDAu;
  x0 += k0; x1 += k1;
#define RR(r) { x0 += x1; x1 = (x1 << (r)) | (x1 >> (32 - (r))); x1 ^= x0; }
  RR(13) RR(15) RR(26) RR(6)   x0 += k1; x1 += k2 + 1u;
  RR(17) RR(29) RR(16) RR(24)  x0 += k2; x1 += k0 + 2u;
  RR(13) RR(15) RR(26) RR(6)   x0 += k0; x1 += k1 + 3u;
  RR(17) RR(29) RR(16) RR(24)  x0 += k1; x1 += k2 + 4u;
  RR(13) RR(15) RR(26) RR(6)   x0 += k2; x1 += k0 + 5u;
#undef RR
}

// partitionable threefry gumbel (bit path verified rounds 2-6); fp32 logs now —
// reference computes gumbel in float32, double was pure overhead.
__device__ __forceinline__ float gumbel_valf(uint32_t n) {
  uint32_t x0 = 0u, x1 = n;
  threefry2x32(0u, 42u, x0, x1);
  uint32_t bits = x0 ^ x1;
  uint32_t fb = (bits >> 9) | 0x3f800000u;
  float f = __uint_as_float(fb) - 1.0f;
  float u = fmaxf(f, 1.1754943508222875e-38f);
  return -logf(-logf(u));
}

// ---------------- kernel A: P = nodes @ W1_top + b1, Q = nodes @ W1_bot ------
__global__ __launch_bounds__(256) void pq_kernel(
    const float* __restrict__ nodes, const float* __restrict__ W1,
    const float* __restrict__ b1, float* __restrict__ P, float* __restrict__ Q) {
  __shared__ float snode[8][FEAT];
  const int row0 = blockIdx.x * 8;
  const int tid = threadIdx.x;
  for (int i = tid; i < 8 * FEAT; i += 256)
    snode[i >> 7][i & 127] = nodes[row0 * FEAT + i];
  __syncthreads();
  const int j = tid & 127;
  const int half = tid >> 7;                   // 0 -> P, 1 -> Q
  const float* w = W1 + half * FEAT * FEAT + j;
  float acc[8] = {0, 0, 0, 0, 0, 0, 0, 0};
  for (int k = 0; k < FEAT; ++k) {
    float wv = w[k * FEAT];
#pragma unroll
    for (int m = 0; m < 8; ++m) acc[m] += snode[m][k] * wv;
  }
  const float bv = half ? 0.0f : b1[j];
  float* out = half ? Q : P;
#pragma unroll
  for (int m = 0; m < 8; ++m) out[(row0 + m) * FEAT + j] = acc[m] + bv;
}

// ---------------- edge index -> (sink, src) ----------------------------------
__global__ __launch_bounds__(256) void map_kernel(int2* __restrict__ map) {
  int e = blockIdx.x * blockDim.x + threadIdx.x;
  if (e >= EDGES) return;
  double x = (double)(e + BASE_OFF);
  int s = (int)((1.0 + sqrt(1.0 + 8.0 * x)) * 0.5);
  while ((long long)s * (s - 1) / 2 - BASE_OFF > e) --s;
  while ((long long)(s + 1) * s / 2 - BASE_OFF <= e) ++s;
  int src = e - (int)((long long)s * (s - 1) / 2 - BASE_OFF);
  map[e] = make_int2(s, src);
}

// ---------------- prep: GTL/GTM = g1-folded W2^T split by k-half -------------
// GTL[n][k] = g1[k]*W2[k][n] for k<64 ; GTM[n][k-64] for k>=64. Plus SG/SB/GW3/SC.
__global__ __launch_bounds__(256) void prep_kernel(
    const float* __restrict__ W2, const float* __restrict__ g1,
    const float* __restrict__ be1, const float* __restrict__ b2,
    const float* __restrict__ g2, const float* __restrict__ be2,
    const float* __restrict__ W3, const float* __restrict__ b3,
    float* __restrict__ GTL, float* __restrict__ GTM,
    float* __restrict__ SG, float* __restrict__ SB,
    float* __restrict__ GW3, float* __restrict__ SC) {
  const int tid = threadIdx.x;
  for (int idx = tid; idx < FEAT * FEAT; idx += 256) {
    const int n = idx >> 7, k = idx & 127;
    const float v = g1[k] * W2[k * FEAT + n];
    if (k < 64) GTL[n * 64 + k] = v;
    else        GTM[n * 64 + (k - 64)] = v;
  }
  if (tid < FEAT) {
    float sg = 0.f, sb = 0.f;
    for (int k = 0; k < FEAT; ++k) {
      float w = W2[k * FEAT + tid];
      sg = fmaf(g1[k], w, sg);
      sb = fmaf(be1[k], w, sb);
    }
    SG[tid] = sg;
    SB[tid] = sb + b2[tid];
    GW3[tid] = g2[tid] * W3[tid];
  }
  __syncthreads();
  if (tid == 0) {
    float a = 0.f, c = 0.f;
    for (int n = 0; n < FEAT; ++n) { a += GW3[n]; c = fmaf(be2[n], W3[n], c); }
    SC[0] = a; SC[1] = c + b3[0];
  }
}

// ---------------- main MLP kernel ---------------------------------------------
// lane = edge; h[128] register-resident. B-operand split across pipes:
// k<64 from LDS (staged once, uniform ds_read_b128 = broadcast, no conflicts),
// k>=64 from VMEM global_load_dwordx4 (asm-opaque zero keeps it vector — the
// scalarizer must NOT turn these into the round-6 serialized s_loads).
__global__ __launch_bounds__(256, 2) void mlp_kernel(
    const float* __restrict__ P, const float* __restrict__ Q,
    const int2* __restrict__ map, const float* __restrict__ GTL,
    const float* __restrict__ GTM,
    const float* __restrict__ SG, const float* __restrict__ SB,
    const float* __restrict__ GW3, const float* __restrict__ SC,
    float* __restrict__ logits) {
  __shared__ float sB[FEAT * 64];            // GTL staged: 32 KB
  const int tid = threadIdx.x;
  const int lane = tid & 63;
  const int wave = tid >> 6;

  {
    const float4* src = (const float4*)GTL;
    float4* dst = (float4*)sB;
    for (int i = tid; i < FEAT * 16; i += 256) dst[i] = src[i];
  }
  __syncthreads();

  const float sgw3 = SC[0], cb = SC[1];
  int z;                                      // opaque zero in a VGPR
  asm volatile("v_mov_b32 %0, 0" : "=v"(z));

#pragma unroll 1
  for (int it = 0; it < 3; ++it) {           // compile-time trip count: uniform
    const int wt = blockIdx.x * 12 + it * 4 + wave;   // < 6120 always
    const int g0 = wt * 64;
    const int b = g0 / EDGES;            // 64 | EDGES: tile never crosses batch
    const int e = (g0 - b * EDGES) + lane;
    const int2 ss = map[e];
    const float4* prow = (const float4*)(P + (((b << 9) + ss.x) << 7));
    const float4* qrow = (const float4*)(Q + (((b << 9) + ss.y) << 7));

    // ---- stage 1: h = relu(P[sink] + Q[src]) into registers; LN1 stats ----
    float4 h4[32];
    float s1 = 0.f, q1 = 0.f;
#pragma unroll
    for (int i = 0; i < 32; ++i) {
      const float4 pv = prow[i];
      const float4 qv = qrow[i];
      float4 h;
      h.x = fmaxf(pv.x + qv.x, 0.f);
      h.y = fmaxf(pv.y + qv.y, 0.f);
      h.z = fmaxf(pv.z + qv.z, 0.f);
      h.w = fmaxf(pv.w + qv.w, 0.f);
      h4[i] = h;
      s1 += (h.x + h.y) + (h.z + h.w);
      q1 = fmaf(h.x, h.x, q1); q1 = fmaf(h.y, h.y, q1);
      q1 = fmaf(h.z, h.z, q1); q1 = fmaf(h.w, h.w, q1);
    }
    const float mu1 = s1 * (1.0f / 128.0f);
    const float var1 = fmaxf(q1 * (1.0f / 128.0f) - mu1 * mu1, 0.0f);
    const float rs1 = rsqrtf(var1 + 1e-5f);

    // ---- stage 2: per n, S = h . GT[n]; B from LDS (k<64) + VMEM (k>=64) ----
    float s2 = 0.f, q2 = 0.f, t = 0.f;
#pragma unroll 1
    for (int n = 0; n < FEAT; ++n) {
      const float4* gm = (const float4*)(GTM + (n << 6)) + z;   // vector loads
      float4 bm[16];
#pragma unroll
      for (int j = 0; j < 16; ++j) bm[j] = gm[j];

      const float4* bl = (const float4*)(sB + (n << 6));        // LDS broadcast
      float a0 = 0.f, a1 = 0.f, a2 = 0.f, a3 = 0.f;
#pragma unroll
      for (int j = 0; j < 16; ++j) {
        const float4 bv = bl[j];
        a0 = fmaf(h4[j].x, bv.x, a0);
        a1 = fmaf(h4[j].y, bv.y, a1);
        a2 = fmaf(h4[j].z, bv.z, a2);
        a3 = fmaf(h4[j].w, bv.w, a3);
      }
#pragma unroll
      for (int j = 0; j < 16; ++j) {
        const float4 bv = bm[j];
        a0 = fmaf(h4[16 + j].x, bv.x, a0);
        a1 = fmaf(h4[16 + j].y, bv.y, a1);
        a2 = fmaf(h4[16 + j].z, bv.z, a2);
        a3 = fmaf(h4[16 + j].w, bv.w, a3);
      }
      const float S = (a0 + a1) + (a2 + a3);
      const float h2 = fmaxf(rs1 * (S - mu1 * SG[n]) + SB[n], 0.f);
      s2 += h2;
      q2 = fmaf(h2, h2, q2);
      t = fmaf(h2, GW3[n], t);
    }
    const float mu2 = s2 * (1.0f / 128.0f);
    const float var2 = fmaxf(q2 * (1.0f / 128.0f) - mu2 * mu2, 0.0f);
    const float rs2 = rsqrtf(var2 + 1e-5f);
    logits[g0 + lane] = rs2 * (t - mu2 * sgw3) + cb;
  }
}

// ---------------- gumbel argmax, stage 1: per-(bs,chunk) best ----------------
__global__ __launch_bounds__(256) void gumbel_kernel(
    const float* __restrict__ logits, float* __restrict__ bestval,
    int* __restrict__ bestidx) {
  const int bs = blockIdx.x / CHUNKS;     // b*5 + s
  const int chunk = blockIdx.x % CHUNKS;
  const int b = bs / NSAMP;
  const float* lg = logits + b * EDGES;
  float best = -1e30f; int bi = 0x7fffffff;
  for (int e = chunk * 256 + threadIdx.x; e < EDGES; e += CHUNKS * 256) {
    uint32_t n = (uint32_t)(bs * EDGES + e);
    float val = lg[e] + gumbel_valf(n);
    if (val > best) { best = val; bi = e; }
  }
  __shared__ float sv[256];
  __shared__ int si[256];
  sv[threadIdx.x] = best; si[threadIdx.x] = bi;
  __syncthreads();
  for (int off = 128; off; off >>= 1) {
    if (threadIdx.x < off) {
      float ov = sv[threadIdx.x + off]; int oi = si[threadIdx.x + off];
      if (ov > sv[threadIdx.x] ||
          (ov == sv[threadIdx.x] && oi < si[threadIdx.x])) {
        sv[threadIdx.x] = ov; si[threadIdx.x] = oi;
      }
    }
    __syncthreads();
  }
  if (threadIdx.x == 0) { bestval[blockIdx.x] = sv[0]; bestidx[blockIdx.x] = si[0]; }
}

// ---------------- gumbel argmax, stage 2: winner -> adj ----------------------
__global__ __launch_bounds__(64) void select_kernel(
    const float* __restrict__ bestval, const int* __restrict__ bestidx,
    const int2* __restrict__ map, float* __restrict__ adj) {
  const int bs = blockIdx.x;
  const int lane = threadIdx.x;
  float v = -1e30f; int idx = 0x7fffffff;
  if (lane < CHUNKS) { v = bestval[bs * CHUNKS + lane]; idx = bestidx[bs * CHUNKS + lane]; }
#pragma unroll
  for (int off = 32; off; off >>= 1) {
    float ov = __shfl_xor(v, off, 64);
    int oi = __shfl_xor(idx, off, 64);
    if (ov > v || (ov == v && oi < idx)) { v = ov; idx = oi; }
  }
  if (lane == 0) {
    int b = bs / NSAMP;
    int2 ss = map[idx];
    adj[((b * NNODES) + ss.x) * NNODES + ss.y] = 1.0f;
  }
}

extern "C" void kernel_launch(void* const* d_in, const int* in_sizes, int n_in,
                              void* d_out, int out_size, void* d_ws, size_t ws_size,
                              hipStream_t stream) {
  const float* nodes = (const float*)d_in[0];
  const float* W1  = (const float*)d_in[1];
  const float* b1  = (const float*)d_in[2];
  const float* g1  = (const float*)d_in[3];
  const float* be1 = (const float*)d_in[4];
  const float* W2  = (const float*)d_in[5];
  const float* b2  = (const float*)d_in[6];
  const float* g2  = (const float*)d_in[7];
  const float* be2 = (const float*)d_in[8];
  const float* W3  = (const float*)d_in[9];
  const float* b3  = (const float*)d_in[10];
  float* adj = (float*)d_out;

  char* ws = (char*)d_ws;
  float* P       = (float*)(ws);                       // 1 MB  [2048][128]
  float* Q       = (float*)(ws + (1 << 20));           // 1 MB
  int2*  map     = (int2*) (ws + (2 << 20));           // 783 KB
  float* logits  = (float*)(ws + (3 << 20));           // 1.57 MB
  float* GTL     = (float*)(ws + (5 << 20));           // 32 KB [n][k<64]
  float* GTM     = (float*)(ws + (5 << 20) + 32768);   // 32 KB [n][k>=64]
  float* SG      = (float*)(ws + (5 << 20) + 65536);
  float* SB      = (float*)(ws + (5 << 20) + 66048);
  float* GW3     = (float*)(ws + (5 << 20) + 66560);
  float* SC      = (float*)(ws + (5 << 20) + 67072);
  float* bestval = (float*)(ws + (5 << 20) + 131072);  // 800*4
  int*   bestidx = (int*)  (ws + (5 << 20) + 137472);  // 800*4

  hipMemsetAsync(adj, 0, (size_t)out_size * sizeof(float), stream);
  pq_kernel<<<(BATCH * NNODES) / 8, 256, 0, stream>>>(nodes, W1, b1, P, Q);
  map_kernel<<<(EDGES + 255) / 256, 256, 0, stream>>>(map);
  prep_kernel<<<1, 256, 0, stream>>>(W2, g1, be1, b2, g2, be2, W3, b3,
                                     GTL, GTM, SG, SB, GW3, SC);
  mlp_kernel<<<MLP_GRID, 256, 0, stream>>>(P, Q, map, GTL, GTM,
                                           SG, SB, GW3, SC, logits);
  gumbel_kernel<<<20 * CHUNKS, 256, 0, stream>>>(logits, bestval, bestidx);
  select_kernel<<<20, 64, 0, stream>>>(bestval, bestidx, map, adj);
}

// Round 8
// 232.988 us; speedup vs baseline: 2.4172x; 2.4172x over previous
//
#include <hip/hip_runtime.h>
#include <stdint.h>

#define FEAT 128
#define NNODES 512
#define BATCH 4
#define EDGES 97920              // sum_{r=257}^{511} r ; 32 | EDGES
#define BE (BATCH*EDGES)         // 391680
#define NSAMP 5
#define BASE_OFF 32896           // 256*257/2
#define CHUNKS 40                // gumbel blocks per (b,s)
#define NWT (BE/32)              // 12240 wave-tiles (32 edges per wave)
#define MLP_GRID 510             // 510 x 4 waves x 6 tiles = 12240 exactly

typedef float f32x4 __attribute__((ext_vector_type(4)));
typedef short s16x8 __attribute__((ext_vector_type(8)));

// ---------------- threefry2x32 (exact JAX core, key=[0,42]) ------------------
__device__ __forceinline__ void threefry2x32(uint32_t k0, uint32_t k1,
                                             uint32_t& x0, uint32_t& x1) {
  uint32_t k2 = k0 ^ k1 ^ 0x1BD11BDAu;
  x0 += k0; x1 += k1;
#define RR(r) { x0 += x1; x1 = (x1 << (r)) | (x1 >> (32 - (r))); x1 ^= x0; }
  RR(13) RR(15) RR(26) RR(6)   x0 += k1; x1 += k2 + 1u;
  RR(17) RR(29) RR(16) RR(24)  x0 += k2; x1 += k0 + 2u;
  RR(13) RR(15) RR(26) RR(6)   x0 += k0; x1 += k1 + 3u;
  RR(17) RR(29) RR(16) RR(24)  x0 += k1; x1 += k2 + 4u;
  RR(13) RR(15) RR(26) RR(6)   x0 += k2; x1 += k0 + 5u;
#undef RR
}

// partitionable threefry gumbel, fp32 logs (verified passing round 7)
__device__ __forceinline__ float gumbel_valf(uint32_t n) {
  uint32_t x0 = 0u, x1 = n;
  threefry2x32(0u, 42u, x0, x1);
  uint32_t bits = x0 ^ x1;
  uint32_t fb = (bits >> 9) | 0x3f800000u;
  float f = __uint_as_float(fb) - 1.0f;
  float u = fmaxf(f, 1.1754943508222875e-38f);
  return -logf(-logf(u));
}

// ---------------- kernel A: P = nodes @ W1_top + b1, Q = nodes @ W1_bot ------
__global__ __launch_bounds__(256) void pq_kernel(
    const float* __restrict__ nodes, const float* __restrict__ W1,
    const float* __restrict__ b1, float* __restrict__ P, float* __restrict__ Q) {
  __shared__ float snode[8][FEAT];
  const int row0 = blockIdx.x * 8;
  const int tid = threadIdx.x;
  for (int i = tid; i < 8 * FEAT; i += 256)
    snode[i >> 7][i & 127] = nodes[row0 * FEAT + i];
  __syncthreads();
  const int j = tid & 127;
  const int half = tid >> 7;                   // 0 -> P, 1 -> Q
  const float* w = W1 + half * FEAT * FEAT + j;
  float acc[8] = {0, 0, 0, 0, 0, 0, 0, 0};
  for (int k = 0; k < FEAT; ++k) {
    float wv = w[k * FEAT];
#pragma unroll
    for (int m = 0; m < 8; ++m) acc[m] += snode[m][k] * wv;
  }
  const float bv = half ? 0.0f : b1[j];
  float* out = half ? Q : P;
#pragma unroll
  for (int m = 0; m < 8; ++m) out[(row0 + m) * FEAT + j] = acc[m] + bv;
}

// ---------------- edge index -> (sink, src) ----------------------------------
__global__ __launch_bounds__(256) void map_kernel(int2* __restrict__ map) {
  int e = blockIdx.x * blockDim.x + threadIdx.x;
  if (e >= EDGES) return;
  double x = (double)(e + BASE_OFF);
  int s = (int)((1.0 + sqrt(1.0 + 8.0 * x)) * 0.5);
  while ((long long)s * (s - 1) / 2 - BASE_OFF > e) --s;
  while ((long long)(s + 1) * s / 2 - BASE_OFF <= e) ++s;
  int src = e - (int)((long long)s * (s - 1) / 2 - BASE_OFF);
  map[e] = make_int2(s, src);
}

// ---------------- prep: B-fragments of G = g1*W2 in bf16 hi/lo, + SB/GW3/SC --
// Fragment order for mfma_f32_16x16x32_bf16 B-operand:
//   GF*[(kt*8+nt)*64 + lane][j] = bf16(G[k][n]),
//   n = nt*16 + (lane&15), k = kt*32 + (lane>>4)*8 + j.
__global__ __launch_bounds__(256) void prep_kernel(
    const float* __restrict__ W2, const float* __restrict__ g1,
    const float* __restrict__ be1, const float* __restrict__ b2,
    const float* __restrict__ g2, const float* __restrict__ be2,
    const float* __restrict__ W3, const float* __restrict__ b3,
    unsigned short* __restrict__ GFH, unsigned short* __restrict__ GFL,
    float* __restrict__ SB, float* __restrict__ GW3, float* __restrict__ SC) {
  const int tid = threadIdx.x;
  for (int idx = tid; idx < FEAT * FEAT; idx += 256) {
    const int j = idx & 7;
    const int lane = (idx >> 3) & 63;
    const int nt = (idx >> 9) & 7;
    const int kt = (idx >> 12) & 3;
    const int n = nt * 16 + (lane & 15);
    const int k = kt * 32 + ((lane >> 4) << 3) + j;
    const float g = g1[k] * W2[k * FEAT + n];
    const uint32_t gu = __float_as_uint(g);
    const float d = g - __uint_as_float(gu & 0xFFFF0000u);
    GFH[idx] = (unsigned short)(gu >> 16);
    GFL[idx] = (unsigned short)(__float_as_uint(d) >> 16);
  }
  if (tid < FEAT) {
    float sb = 0.f;
    for (int k = 0; k < FEAT; ++k)
      sb = fmaf(be1[k], W2[k * FEAT + tid], sb);
    SB[tid] = sb + b2[tid];
    GW3[tid] = g2[tid] * W3[tid];
  }
  __syncthreads();
  if (tid == 0) {
    float a = 0.f, c = 0.f;
    for (int n = 0; n < FEAT; ++n) { a += GW3[n]; c = fmaf(be2[n], W3[n], c); }
    SC[0] = a; SC[1] = c + b3[0];
  }
}

// ---------------- main MLP kernel (MFMA) --------------------------------------
// Per wave: 32 edges. Stage 1: lane-pair = edge, h -> per-wave LDS [32][132]
// (cols 128/129 hold mu, rstd). Stage 2: 3-product bf16-split MFMA GEMM
// (M=32,N=128,K=128): A from LDS (normalize+split fused into frag load),
// B from prep's fragment-ordered global arrays (coalesced dwordx4, L1/L2-hot).
// Epilogue: relu(S+SB), folded LN2+W3, 16-lane shuffle reductions.
__global__ __launch_bounds__(256, 2) void mlp_kernel(
    const float* __restrict__ P, const float* __restrict__ Q,
    const int2* __restrict__ map,
    const unsigned short* __restrict__ GFH,
    const unsigned short* __restrict__ GFL,
    const float* __restrict__ SB, const float* __restrict__ GW3,
    const float* __restrict__ SC, float* __restrict__ logits) {
  __shared__ float sx[4][32 * 132];          // 4 x 16.9 KB = 67.6 KB
  const int tid = threadIdx.x;
  const int lane = tid & 63;
  const int wave = tid >> 6;
  const int cl = lane & 15;                   // col / m-in-tile lane
  const int qd = lane >> 4;                   // quad index
  float* sxw = sx[wave];
  const s16x8* bfh = (const s16x8*)GFH;
  const s16x8* bfl = (const s16x8*)GFL;

  float SBv[8], GWv[8];
#pragma unroll
  for (int nt = 0; nt < 8; ++nt) {
    SBv[nt] = SB[nt * 16 + cl];
    GWv[nt] = GW3[nt * 16 + cl];
  }
  const float sgw3 = SC[0], cb = SC[1];

#pragma unroll 1
  for (int it = 0; it < 6; ++it) {           // uniform trip count
    const int wt = blockIdx.x * 24 + it * 4 + wave;   // < 12240 always
    const int g0 = wt * 32;
    const int b = g0 / EDGES;                // 32 | EDGES: no batch crossing
    const int e = (g0 - b * EDGES) + (lane >> 1);
    const int2 ss = map[e];
    const int hh = lane & 1;                 // which 64-feature half

    // ---- stage 1: h = relu(P[sink]+Q[src]) -> LDS; LN1 stats per edge ----
    const float4* prow = (const float4*)(P + (((b << 9) + ss.x) << 7) + (hh << 6));
    const float4* qrow = (const float4*)(Q + (((b << 9) + ss.y) << 7) + (hh << 6));
    float* srow = sxw + (lane >> 1) * 132 + (hh << 6);
    float s1 = 0.f, q1 = 0.f;
#pragma unroll
    for (int i = 0; i < 16; ++i) {
      const float4 pv = prow[i];
      const float4 qv = qrow[i];
      float4 h;
      h.x = fmaxf(pv.x + qv.x, 0.f);
      h.y = fmaxf(pv.y + qv.y, 0.f);
      h.z = fmaxf(pv.z + qv.z, 0.f);
      h.w = fmaxf(pv.w + qv.w, 0.f);
      *(float4*)(srow + i * 4) = h;
      s1 += (h.x + h.y) + (h.z + h.w);
      q1 = fmaf(h.x, h.x, q1); q1 = fmaf(h.y, h.y, q1);
      q1 = fmaf(h.z, h.z, q1); q1 = fmaf(h.w, h.w, q1);
    }
    s1 += __shfl_xor(s1, 1, 64);
    q1 += __shfl_xor(q1, 1, 64);
    const float mu = s1 * (1.0f / 128.0f);
    const float var = fmaxf(q1 * (1.0f / 128.0f) - mu * mu, 0.0f);
    const float rs = rsqrtf(var + 1e-5f);
    if (hh == 0) {
      float* st = sxw + (lane >> 1) * 132;
      st[128] = mu;
      st[129] = rs;
    }
    __builtin_amdgcn_wave_barrier();

    // per-m-tile LN1 constants for the A-fragment rows this lane serves
    float rs_m[2], nm_m[2];
#pragma unroll
    for (int mt = 0; mt < 2; ++mt) {
      const float* st = sxw + (mt * 16 + cl) * 132;
      const float m_mu = st[128];
      const float m_rs = st[129];
      rs_m[mt] = m_rs;
      nm_m[mt] = -m_mu * m_rs;
    }

    // ---- stage 2: S = x̂ @ G via 3-product bf16-split MFMA ----
    f32x4 acc[2][8];
#pragma unroll
    for (int mt = 0; mt < 2; ++mt)
#pragma unroll
      for (int nt = 0; nt < 8; ++nt) acc[mt][nt] = (f32x4){0.f, 0.f, 0.f, 0.f};

#pragma unroll
    for (int kt = 0; kt < 4; ++kt) {
      // B fragments (hi/lo), coalesced 16B loads
      s16x8 Bh[8], Bl[8];
#pragma unroll
      for (int nt = 0; nt < 8; ++nt) {
        const int fi = (kt * 8 + nt) * 64 + lane;
        Bh[nt] = bfh[fi];
        Bl[nt] = bfl[fi];
      }
      // A fragments: read raw h, normalize, split hi/lo
      s16x8 Ah[2], Al[2];
#pragma unroll
      for (int mt = 0; mt < 2; ++mt) {
        const float* ap = sxw + (mt * 16 + cl) * 132 + qd * 8 + kt * 32;
        const float4 u0 = *(const float4*)ap;
        const float4 u1 = *(const float4*)(ap + 4);
        const float uu[8] = {u0.x, u0.y, u0.z, u0.w, u1.x, u1.y, u1.z, u1.w};
#pragma unroll
        for (int j = 0; j < 8; ++j) {
          const float xh = fmaf(uu[j], rs_m[mt], nm_m[mt]);
          const uint32_t xu = __float_as_uint(xh);
          const float d = xh - __uint_as_float(xu & 0xFFFF0000u);
          Ah[mt][j] = (short)(xu >> 16);
          Al[mt][j] = (short)(__float_as_uint(d) >> 16);
        }
      }
      // three sweeps keep each acc's dependent MFMAs 16 issues apart
#pragma unroll
      for (int nt = 0; nt < 8; ++nt) {
        acc[0][nt] = __builtin_amdgcn_mfma_f32_16x16x32_bf16(Ah[0], Bh[nt], acc[0][nt], 0, 0, 0);
        acc[1][nt] = __builtin_amdgcn_mfma_f32_16x16x32_bf16(Ah[1], Bh[nt], acc[1][nt], 0, 0, 0);
      }
#pragma unroll
      for (int nt = 0; nt < 8; ++nt) {
        acc[0][nt] = __builtin_amdgcn_mfma_f32_16x16x32_bf16(Al[0], Bh[nt], acc[0][nt], 0, 0, 0);
        acc[1][nt] = __builtin_amdgcn_mfma_f32_16x16x32_bf16(Al[1], Bh[nt], acc[1][nt], 0, 0, 0);
      }
#pragma unroll
      for (int nt = 0; nt < 8; ++nt) {
        acc[0][nt] = __builtin_amdgcn_mfma_f32_16x16x32_bf16(Ah[0], Bl[nt], acc[0][nt], 0, 0, 0);
        acc[1][nt] = __builtin_amdgcn_mfma_f32_16x16x32_bf16(Ah[1], Bl[nt], acc[1][nt], 0, 0, 0);
      }
    }

    // ---- epilogue: h2 = relu(S + SB[n]); folded LN2 + W3 ----
#pragma unroll
    for (int mt = 0; mt < 2; ++mt) {
      float sr[4] = {0.f, 0.f, 0.f, 0.f};
      float qr[4] = {0.f, 0.f, 0.f, 0.f};
      float tr[4] = {0.f, 0.f, 0.f, 0.f};
#pragma unroll
      for (int nt = 0; nt < 8; ++nt) {
        const f32x4 a = acc[mt][nt];
#pragma unroll
        for (int r = 0; r < 4; ++r) {
          const float h2 = fmaxf(a[r] + SBv[nt], 0.f);
          sr[r] += h2;
          qr[r] = fmaf(h2, h2, qr[r]);
          tr[r] = fmaf(h2, GWv[nt], tr[r]);
        }
      }
#pragma unroll
      for (int r = 0; r < 4; ++r) {
        float s2 = sr[r], q2 = qr[r], t = tr[r];
#pragma unroll
        for (int off = 1; off < 16; off <<= 1) {
          s2 += __shfl_xor(s2, off, 64);
          q2 += __shfl_xor(q2, off, 64);
          t  += __shfl_xor(t,  off, 64);
        }
        if (cl == 0) {
          const float mu2 = s2 * (1.0f / 128.0f);
          const float var2 = fmaxf(q2 * (1.0f / 128.0f) - mu2 * mu2, 0.0f);
          const float rs2 = rsqrtf(var2 + 1e-5f);
          logits[g0 + mt * 16 + qd * 4 + r] = rs2 * (t - mu2 * sgw3) + cb;
        }
      }
    }
    __builtin_amdgcn_wave_barrier();
  }
}

// ---------------- gumbel argmax, stage 1: per-(bs,chunk) best ----------------
__global__ __launch_bounds__(256) void gumbel_kernel(
    const float* __restrict__ logits, float* __restrict__ bestval,
    int* __restrict__ bestidx) {
  const int bs = blockIdx.x / CHUNKS;     // b*5 + s
  const int chunk = blockIdx.x % CHUNKS;
  const int b = bs / NSAMP;
  const float* lg = logits + b * EDGES;
  float best = -1e30f; int bi = 0x7fffffff;
  for (int e = chunk * 256 + threadIdx.x; e < EDGES; e += CHUNKS * 256) {
    uint32_t n = (uint32_t)(bs * EDGES + e);
    float val = lg[e] + gumbel_valf(n);
    if (val > best) { best = val; bi = e; }
  }
  __shared__ float sv[256];
  __shared__ int si[256];
  sv[threadIdx.x] = best; si[threadIdx.x] = bi;
  __syncthreads();
  for (int off = 128; off; off >>= 1) {
    if (threadIdx.x < off) {
      float ov = sv[threadIdx.x + off]; int oi = si[threadIdx.x + off];
      if (ov > sv[threadIdx.x] ||
          (ov == sv[threadIdx.x] && oi < si[threadIdx.x])) {
        sv[threadIdx.x] = ov; si[threadIdx.x] = oi;
      }
    }
    __syncthreads();
  }
  if (threadIdx.x == 0) { bestval[blockIdx.x] = sv[0]; bestidx[blockIdx.x] = si[0]; }
}

// ---------------- gumbel argmax, stage 2: winner -> adj ----------------------
__global__ __launch_bounds__(64) void select_kernel(
    const float* __restrict__ bestval, const int* __restrict__ bestidx,
    const int2* __restrict__ map, float* __restrict__ adj) {
  const int bs = blockIdx.x;
  const int lane = threadIdx.x;
  float v = -1e30f; int idx = 0x7fffffff;
  if (lane < CHUNKS) { v = bestval[bs * CHUNKS + lane]; idx = bestidx[bs * CHUNKS + lane]; }
#pragma unroll
  for (int off = 32; off; off >>= 1) {
    float ov = __shfl_xor(v, off, 64);
    int oi = __shfl_xor(idx, off, 64);
    if (ov > v || (ov == v && oi < idx)) { v = ov; idx = oi; }
  }
  if (lane == 0) {
    int b = bs / NSAMP;
    int2 ss = map[idx];
    adj[((b * NNODES) + ss.x) * NNODES + ss.y] = 1.0f;
  }
}

extern "C" void kernel_launch(void* const* d_in, const int* in_sizes, int n_in,
                              void* d_out, int out_size, void* d_ws, size_t ws_size,
                              hipStream_t stream) {
  const float* nodes = (const float*)d_in[0];
  const float* W1  = (const float*)d_in[1];
  const float* b1  = (const float*)d_in[2];
  const float* g1  = (const float*)d_in[3];
  const float* be1 = (const float*)d_in[4];
  const float* W2  = (const float*)d_in[5];
  const float* b2  = (const float*)d_in[6];
  const float* g2  = (const float*)d_in[7];
  const float* be2 = (const float*)d_in[8];
  const float* W3  = (const float*)d_in[9];
  const float* b3  = (const float*)d_in[10];
  float* adj = (float*)d_out;

  char* ws = (char*)d_ws;
  float* P       = (float*)(ws);                       // 1 MB  [2048][128]
  float* Q       = (float*)(ws + (1 << 20));           // 1 MB
  int2*  map     = (int2*) (ws + (2 << 20));           // 783 KB
  float* logits  = (float*)(ws + (3 << 20));           // 1.57 MB
  unsigned short* GFH = (unsigned short*)(ws + (5 << 20));           // 32 KB
  unsigned short* GFL = (unsigned short*)(ws + (5 << 20) + 32768);   // 32 KB
  float* SB      = (float*)(ws + (5 << 20) + 66048);
  float* GW3     = (float*)(ws + (5 << 20) + 66560);
  float* SC      = (float*)(ws + (5 << 20) + 67072);
  float* bestval = (float*)(ws + (5 << 20) + 131072);  // 800*4
  int*   bestidx = (int*)  (ws + (5 << 20) + 137472);  // 800*4

  hipMemsetAsync(adj, 0, (size_t)out_size * sizeof(float), stream);
  pq_kernel<<<(BATCH * NNODES) / 8, 256, 0, stream>>>(nodes, W1, b1, P, Q);
  map_kernel<<<(EDGES + 255) / 256, 256, 0, stream>>>(map);
  prep_kernel<<<1, 256, 0, stream>>>(W2, g1, be1, b2, g2, be2, W3, b3,
                                     GFH, GFL, SB, GW3, SC);
  mlp_kernel<<<MLP_GRID, 256, 0, stream>>>(P, Q, map, GFH, GFL,
                                           SB, GW3, SC, logits);
  gumbel_kernel<<<20 * CHUNKS, 256, 0, stream>>>(logits, bestval, bestidx);
  select_kernel<<<20, 64, 0, stream>>>(bestval, bestidx, map, adj);
}